// Round 8
// baseline (408.747 us; speedup 1.0000x reference)
//
#include <hip/hip_runtime.h>

// Problem constants
#define N_LIC 40000
#define N_EMP 80000
#define N_CON 60000
#define D_EMP 128
#define D_CON 192
#define HDIM  256
#define E_P   1280000
#define E_Q   640000
#define E_T   (E_P + E_Q)

#define NSEG  64            // sub-ranges per relation (625 dst each)
#define SEGW  (2 * NSEG)    // 128 total segments
#define SUBR  (N_LIC / NSEG) // 625 dst per segment

// -------------------- workspace layout (4-byte units) --------------------
// Total ~62.4 MB
#define OFF_AGGP   0                                   // 40000x128 bf16 -> 2,560,000 dw
#define OFF_STG    OFF_AGGP                            // ALIAS: packed-edge staging 1,920,000 dw
#define OFF_XE     (OFF_AGGP + 2560000)                // 80000x128 bf16 -> 5,120,000 dw
#define OFF_AGGQ   OFF_XE                              // ALIAS: aggq reuses xe (xe dead after aggP)
#define OFF_XC     (OFF_XE + 5120000)                  // 60000x192 bf16 -> 5,760,000 dw
#define OFF_BPK    (OFF_XC + 5760000)                  // 256x576 bf16 -> 73,728 dw
#define OFF_BIAS   (OFF_BPK + 73728)                   // 256 f
#define OFF_CNT    (OFF_BIAS + 256)                    // 80000 i (P then Q)
#define OFF_SEGT   (OFF_CNT + 2 * N_LIC)               // 128 i seg totals
#define OFF_SEGB   (OFF_SEGT + 128)                    // 128 i seg bases
#define OFF_SEGC   (OFF_SEGB + 128)                    // 128 i seg cursors
#define OFF_OFFP   (OFF_SEGC + 128)                    // 40000 i
#define OFF_OFFQ   (OFF_OFFP + N_LIC)                  // 40000 i
#define OFF_SRTP   (OFF_OFFQ + N_LIC)                  // 1,280,000 i
#define OFF_SRTQ   (OFF_SRTP + E_P)                    // 640,000 i

typedef short bf16x8 __attribute__((ext_vector_type(8)));
typedef float f32x4 __attribute__((ext_vector_type(4)));

__device__ __forceinline__ ushort f2bf(float f) {
    union { float f; uint u; } v; v.f = f;
    return (ushort)((v.u + 0x7fffu + ((v.u >> 16) & 1u)) >> 16);
}

__device__ __forceinline__ void acc2(uint u, float& lo, float& hi) {
    union { uint u; float f; } a, b;
    a.u = u << 16;
    b.u = u & 0xffff0000u;
    lo += a.f; hi += b.f;
}

__device__ __forceinline__ uint packbf(float lo, float hi) {
    return (uint)f2bf(lo) | ((uint)f2bf(hi) << 16);
}

// -------------------- prep: pack B = [Wl_p; Wl_q; Wr_p+Wr_q] transposed to [n][k] bf16 ----
__global__ void prep_kernel(const float* __restrict__ Wlp, const float* __restrict__ Wlq,
                            const float* __restrict__ Wrp, const float* __restrict__ Wrq,
                            const float* __restrict__ bp, const float* __restrict__ bq,
                            ushort* __restrict__ Bpk, float* __restrict__ bias) {
    int tid = blockIdx.x * 256 + threadIdx.x;
    if (tid < 256 * 576) {
        int n = tid / 576, k = tid - n * 576;
        float v;
        if (k < 128)      v = Wlp[k * 256 + n];
        else if (k < 320) v = Wlq[(k - 128) * 256 + n];
        else              v = Wrp[(k - 320) * 256 + n] + Wrq[(k - 320) * 256 + n];
        Bpk[tid] = f2bf(v);
    } else if (tid < 256 * 576 + 256) {
        int j = tid - 256 * 576;
        bias[j] = bp[j] + bq[j];
    }
}

// -------------------- fused fp32->bf16 conversion of x_emp, x_con --------------------
#define C_XE (N_EMP * 128 / 4)   // 2,560,000 float4s
#define C_XC (N_CON * 192 / 4)   // 2,880,000
__global__ void convert2_kernel(const float* __restrict__ xemp, const float* __restrict__ xcon,
                                ushort* __restrict__ xe, ushort* __restrict__ xc) {
    int tid = blockIdx.x * 256 + threadIdx.x;
    const float* src; ushort* dst; int i;
    if (tid < C_XE) { src = xemp; dst = xe; i = tid; }
    else            { src = xcon; dst = xc; i = tid - C_XE; }
    float4 v = ((const float4*)src)[i];
    uint2 o;
    o.x = packbf(v.x, v.y);
    o.y = packbf(v.z, v.w);
    ((uint2*)dst)[i] = o;
}

// -------------------- pre-count: 128 (rel,subrange) totals, LDS-aggregated --------------------
__global__ __launch_bounds__(256) void precount_kernel(const int* __restrict__ dp,
                                                       const int* __restrict__ dq,
                                                       int* __restrict__ segtot) {
    __shared__ int lc[SEGW];
    int t = threadIdx.x;
    if (t < SEGW) lc[t] = 0;
    __syncthreads();
    int base = blockIdx.x * 2048 + t;
    #pragma unroll
    for (int i = 0; i < 8; i++) {
        int e = base + i * 256;
        if (e < E_T) {
            int d, rel;
            if (e < E_P) { d = __builtin_nontemporal_load(&dp[e]); rel = 0; }
            else         { d = __builtin_nontemporal_load(&dq[e - E_P]); rel = 1; }
            atomicAdd(&lc[rel * NSEG + d / SUBR], 1);
        }
    }
    __syncthreads();
    if (t < SEGW && lc[t] > 0) atomicAdd(&segtot[t], lc[t]);
}

// -------------------- seg bases: exclusive scan of 128 totals --------------------
// Scan order puts all P segments (s<64) in stg[0,E_P), Q segments in [E_P,E_T).
__global__ void segbase_kernel(const int* __restrict__ segtot,
                               int* __restrict__ segbase, int* __restrict__ segcur) {
    if (threadIdx.x == 0) {
        int run = 0;
        for (int i = 0; i < SEGW; i++) {
            segbase[i] = run; segcur[i] = run;
            run += segtot[i];
        }
    }
}

// -------------------- partition: edges -> 128 segments, ALL global writes coalesced ----------
// gfx950 L2 does not write-allocate scattered 4B stores (R4/R6: ~9x write amp regardless of
// affinity). So: sort the block's 2048 edges by segment in LDS, claim per-seg spans, then
// copy out with consecutive threads -> consecutive addresses.
__global__ __launch_bounds__(256) void partition_kernel(const int* __restrict__ sp,
                                                        const int* __restrict__ dp,
                                                        const int* __restrict__ sq,
                                                        const int* __restrict__ dq,
                                                        int* __restrict__ segcur,
                                                        uint* __restrict__ stg) {
    __shared__ int lc[SEGW], inc[SEGW], lb[SEGW], gb[SEGW];
    __shared__ uint srtd[2048];
    __shared__ uchar sid[2048];
    int t = threadIdx.x;
    if (t < SEGW) lc[t] = 0;
    __syncthreads();
    int seg[8], lo[8]; uint pk[8];
    int base = blockIdx.x * 2048 + t;
    #pragma unroll
    for (int i = 0; i < 8; i++) {
        int e = base + i * 256;
        seg[i] = -1;
        if (e < E_T) {
            int d, s, rel;
            if (e < E_P) {
                d = __builtin_nontemporal_load(&dp[e]);
                s = __builtin_nontemporal_load(&sp[e]); rel = 0;
            } else {
                int eq = e - E_P;
                d = __builtin_nontemporal_load(&dq[eq]);
                s = __builtin_nontemporal_load(&sq[eq]); rel = 1;
            }
            int sl = d / SUBR;
            int dl = d - sl * SUBR;
            seg[i] = rel * NSEG + sl;
            pk[i] = ((uint)dl << 17) | (uint)s;
            lo[i] = atomicAdd(&lc[seg[i]], 1);
        }
    }
    __syncthreads();
    if (t < SEGW) inc[t] = lc[t];
    __syncthreads();
    #pragma unroll
    for (int off = 1; off < SEGW; off <<= 1) {
        int v = (t >= off && t < SEGW) ? inc[t - off] : 0;
        __syncthreads();
        if (t < SEGW) inc[t] += v;
        __syncthreads();
    }
    if (t < SEGW) {
        lb[t] = inc[t] - lc[t];
        gb[t] = lc[t] > 0 ? atomicAdd(&segcur[t], lc[t]) : 0;
    }
    __syncthreads();
    #pragma unroll
    for (int i = 0; i < 8; i++) {
        if (seg[i] >= 0) {
            int p = lb[seg[i]] + lo[i];
            srtd[p] = pk[i];
            sid[p] = (uchar)seg[i];
        }
    }
    __syncthreads();
    int tot = inc[SEGW - 1];
    for (int p = t; p < tot; p += 256) {
        int s = sid[p];
        stg[gb[s] + (p - lb[s])] = srtd[p];
    }
}

// -------------------- per-segment in-LDS counting sort -> srt, offs, cnt --------------------
#define LCAP 22528   // 88 KB sorted buffer; P seg mean 20000, sd ~140 -> 18 sigma margin
__global__ __launch_bounds__(1024) void sort_kernel(const int* __restrict__ segbase,
                                                    const int* __restrict__ segcur,
                                                    const uint* __restrict__ stg,
                                                    int* __restrict__ srtp, int* __restrict__ srtq,
                                                    int* __restrict__ offp, int* __restrict__ offq,
                                                    int* __restrict__ cnt) {
    __shared__ int lcnt[SUBR], lcur[SUBR];
    __shared__ int sc[640];
    __shared__ uint buf[LCAP];
    int s = blockIdx.x;
    int rel = s >> 6;
    int beg = segbase[s], end = segcur[s];
    int t = threadIdx.x;
    if (t < SUBR) { lcnt[t] = 0; lcur[t] = 0; }
    __syncthreads();
    for (int idx = beg + t; idx < end; idx += 1024)
        atomicAdd(&lcnt[stg[idx] >> 17], 1);
    __syncthreads();
    if (t < 640) sc[t] = (t < SUBR) ? lcnt[t] : 0;
    __syncthreads();
    #pragma unroll
    for (int off = 1; off < 640; off <<= 1) {
        int v = (t >= off && t < 640) ? sc[t - off] : 0;
        __syncthreads();
        if (t < 640) sc[t] += v;
        __syncthreads();
    }
    int rb = (rel == 0) ? beg : beg - E_P;
    int* srt = (rel == 0) ? srtp : srtq;
    for (int idx = beg + t; idx < end; idx += 1024) {
        uint p = stg[idx];
        int dl = (int)(p >> 17);
        int pos = sc[dl] - lcnt[dl] + atomicAdd(&lcur[dl], 1);
        uint sv = p & 0x1FFFFu;
        if (pos < LCAP) buf[pos] = sv;
        else srt[rb + pos] = (int)sv;   // astronomically rare overflow fallback
    }
    __syncthreads();
    int n = end - beg;
    int m = n < LCAP ? n : LCAP;
    for (int p = t; p < m; p += 1024) srt[rb + p] = (int)buf[p];
    int dbase = (s & (NSEG - 1)) * SUBR;
    int* offs = (rel == 0) ? offp : offq;
    int* cn = (rel == 0) ? cnt : cnt + N_LIC;
    if (t < SUBR) {
        offs[dbase + t] = rb + sc[t] - lcnt[t];
        cn[dbase + t] = lcnt[t];
    }
}

// -------------------- aggregate P: 16 lanes/node, D=128 bf16 in -> bf16 out ------------
__global__ __launch_bounds__(256) void aggP_kernel(const ushort* __restrict__ xe,
                                                   const int* __restrict__ offs,
                                                   const int* __restrict__ cnt,
                                                   const int* __restrict__ sorted,
                                                   ushort* __restrict__ agg) {
    int g = blockIdx.x * 16 + (threadIdx.x >> 4);
    int c = threadIdx.x & 15;
    int beg = offs[g], deg = cnt[g], end = beg + deg;
    float a0=0,a1=0,a2=0,a3=0,a4=0,a5=0,a6=0,a7=0;
    for (int eb = beg; eb < end; eb += 16) {
        int n = end - eb; if (n > 16) n = 16;
        int my = (c < n) ? sorted[eb + c] : 0;
        for (int j = 0; j < n; j++) {
            int s = __shfl(my, j, 16);
            uint4 v = *(const uint4*)(xe + (size_t)s * D_EMP + c * 8);
            acc2(v.x, a0, a1); acc2(v.y, a2, a3);
            acc2(v.z, a4, a5); acc2(v.w, a6, a7);
        }
    }
    float inv = 1.0f / fmaxf((float)deg, 1.0f);
    uint4 o;
    o.x = packbf(a0 * inv, a1 * inv);
    o.y = packbf(a2 * inv, a3 * inv);
    o.z = packbf(a4 * inv, a5 * inv);
    o.w = packbf(a6 * inv, a7 * inv);
    *(uint4*)(agg + (size_t)g * D_EMP + c * 8) = o;
}

// -------------------- aggregate Q: 16 lanes/node, D=192 bf16 in -> bf16 out ------------
__global__ __launch_bounds__(256) void aggQ_kernel(const ushort* __restrict__ xc,
                                                   const int* __restrict__ offs,
                                                   const int* __restrict__ cnt,
                                                   const int* __restrict__ sorted,
                                                   ushort* __restrict__ agg) {
    int g = blockIdx.x * 16 + (threadIdx.x >> 4);
    int c = threadIdx.x & 15;
    int beg = offs[g], deg = cnt[g], end = beg + deg;
    float a0=0,a1=0,a2=0,a3=0,a4=0,a5=0,a6=0,a7=0,a8=0,a9=0,a10=0,a11=0;
    for (int eb = beg; eb < end; eb += 16) {
        int n = end - eb; if (n > 16) n = 16;
        int my = (c < n) ? sorted[eb + c] : 0;
        for (int j = 0; j < n; j++) {
            int s = __shfl(my, j, 16);
            const ushort* row = xc + (size_t)s * D_CON + c * 12;
            uint2 v0 = *(const uint2*)(row + 0);
            uint2 v1 = *(const uint2*)(row + 4);
            uint2 v2 = *(const uint2*)(row + 8);
            acc2(v0.x, a0, a1);  acc2(v0.y, a2, a3);
            acc2(v1.x, a4, a5);  acc2(v1.y, a6, a7);
            acc2(v2.x, a8, a9);  acc2(v2.y, a10, a11);
        }
    }
    float inv = 1.0f / fmaxf((float)deg, 1.0f);
    ushort* o = agg + (size_t)g * D_CON + c * 12;
    uint2 w0, w1, w2;
    w0.x = packbf(a0 * inv, a1 * inv);   w0.y = packbf(a2 * inv, a3 * inv);
    w1.x = packbf(a4 * inv, a5 * inv);   w1.y = packbf(a6 * inv, a7 * inv);
    w2.x = packbf(a8 * inv, a9 * inv);   w2.y = packbf(a10 * inv, a11 * inv);
    *(uint2*)(o + 0) = w0;
    *(uint2*)(o + 4) = w1;
    *(uint2*)(o + 8) = w2;
}

// -------------------- MFMA bf16 GEMM + bias + relu (LDS-free, barrier-free) --------------------
// C[40000,256] = relu(0.5*([aggp|aggq|bf16(x_lic)] @ B + bias)); B prepacked [n=256][k=576].
// K=576 is tiny: MFMA fragments (8 contiguous bf16 in k per lane) are loaded DIRECTLY from
// global via one dwordx4 each. No LDS, no barriers, no bank conflicts; 9.8 free-running
// waves/CU hide L2 latency (R7: barrier-synced LDS version was latency-bound at 7% MfmaUtil).
// B (288 KB) is L2-resident; the 4 col-waves of a block share A lines via L1.
__global__ __launch_bounds__(256) void gemm_kernel(
    const ushort* __restrict__ aggp, const ushort* __restrict__ aggq,
    const float* __restrict__ xlic, const ushort* __restrict__ Bpk,
    const float* __restrict__ bias, float* __restrict__ out)
{
    const int t = threadIdx.x;
    const int m0 = blockIdx.x * 64;
    const int lane = t & 63;
    const int wave = t >> 6;
    const int l15 = lane & 15;
    const int lh  = lane >> 4; // 0..3

    f32x4 acc[4][4];
    #pragma unroll
    for (int i = 0; i < 4; i++)
        #pragma unroll
        for (int j = 0; j < 4; j++)
            acc[i][j] = (f32x4){0.f, 0.f, 0.f, 0.f};

    const ushort* Bbase = Bpk + (size_t)(wave * 64 + l15) * 576 + lh * 8;

    for (int k0 = 0; k0 < 576; k0 += 32) {
        bf16x8 af[4], bfr[4];
        // B fragments: col = wave*64 + nt*16 + l15, k = k0 + lh*8 (8 contiguous bf16)
        #pragma unroll
        for (int nt = 0; nt < 4; nt++)
            bfr[nt] = *(const bf16x8*)(Bbase + (size_t)nt * 16 * 576 + k0);
        // A fragments: row = m0 + mt*16 + l15, k-chunk lh*8
        if (k0 < 128) {
            #pragma unroll
            for (int mt = 0; mt < 4; mt++)
                af[mt] = *(const bf16x8*)(aggp + (size_t)(m0 + mt * 16 + l15) * 128 + k0 + lh * 8);
        } else if (k0 < 320) {
            #pragma unroll
            for (int mt = 0; mt < 4; mt++)
                af[mt] = *(const bf16x8*)(aggq + (size_t)(m0 + mt * 16 + l15) * 192 + (k0 - 128) + lh * 8);
        } else {
            #pragma unroll
            for (int mt = 0; mt < 4; mt++) {
                const float* src = xlic + (size_t)(m0 + mt * 16 + l15) * 256 + (k0 - 320) + lh * 8;
                float4 v0 = *(const float4*)(src + 0);
                float4 v1 = *(const float4*)(src + 4);
                union { uint4 u; bf16x8 b; } cv;
                cv.u.x = packbf(v0.x, v0.y);
                cv.u.y = packbf(v0.z, v0.w);
                cv.u.z = packbf(v1.x, v1.y);
                cv.u.w = packbf(v1.z, v1.w);
                af[mt] = cv.b;
            }
        }
        #pragma unroll
        for (int mt = 0; mt < 4; mt++)
            #pragma unroll
            for (int nt = 0; nt < 4; nt++)
                acc[mt][nt] = __builtin_amdgcn_mfma_f32_16x16x32_bf16(af[mt], bfr[nt], acc[mt][nt], 0, 0, 0);
    }

    // epilogue: C/D layout col=lane&15, row=(lane>>4)*4+reg
    #pragma unroll
    for (int nt = 0; nt < 4; nt++) {
        int n = wave * 64 + nt * 16 + l15;
        float bv = bias[n];
        #pragma unroll
        for (int mt = 0; mt < 4; mt++) {
            #pragma unroll
            for (int r = 0; r < 4; r++) {
                int m = m0 + mt * 16 + lh * 4 + r;
                float v = 0.5f * (acc[mt][nt][r] + bv);
                out[(size_t)m * 256 + n] = fmaxf(v, 0.f);
            }
        }
    }
}

// -------------------- launch --------------------
extern "C" void kernel_launch(void* const* d_in, const int* in_sizes, int n_in,
                              void* d_out, int out_size, void* d_ws, size_t ws_size,
                              hipStream_t stream) {
    const float* x_lic = (const float*)d_in[0];
    const float* x_emp = (const float*)d_in[1];
    const float* x_con = (const float*)d_in[2];
    const float* Wl_p  = (const float*)d_in[3];
    const float* Wr_p  = (const float*)d_in[4];
    const float* b_p   = (const float*)d_in[5];
    const float* Wl_q  = (const float*)d_in[6];
    const float* Wr_q  = (const float*)d_in[7];
    const float* b_q   = (const float*)d_in[8];
    const int* ei_p_src = (const int*)d_in[9];
    const int* ei_p_dst = (const int*)d_in[10];
    const int* ei_q_src = (const int*)d_in[11];
    const int* ei_q_dst = (const int*)d_in[12];

    float* ws = (float*)d_ws;
    ushort* aggp = (ushort*)(ws + OFF_AGGP);
    ushort* aggq = (ushort*)(ws + OFF_AGGQ);   // aliases xe
    uint*  stg  = (uint*)(ws + OFF_STG);       // aliases aggp
    ushort* xe   = (ushort*)(ws + OFF_XE);
    ushort* xc   = (ushort*)(ws + OFF_XC);
    ushort* Bpk  = (ushort*)(ws + OFF_BPK);
    float* bias  = ws + OFF_BIAS;
    int* cnt  = (int*)(ws + OFF_CNT);
    int* segt = (int*)(ws + OFF_SEGT);
    int* segb = (int*)(ws + OFF_SEGB);
    int* segc = (int*)(ws + OFF_SEGC);
    int* offp = (int*)(ws + OFF_OFFP);
    int* offq = (int*)(ws + OFF_OFFQ);
    int* srtp = (int*)(ws + OFF_SRTP);
    int* srtq = (int*)(ws + OFF_SRTQ);
    float* out = (float*)d_out;

    // only segtot needs zeroing (cnt/offs fully written by sort_kernel)
    hipMemsetAsync(segt, 0, SEGW * sizeof(int), stream);

    prep_kernel<<<(256 * 576 + 256 + 255) / 256, 256, 0, stream>>>(Wl_p, Wl_q, Wr_p, Wr_q, b_p, b_q, Bpk, bias);

    convert2_kernel<<<(C_XE + C_XC) / 256, 256, 0, stream>>>(x_emp, x_con, xe, xc);

    const int NBP = (E_T + 2047) / 2048;   // 938 blocks
    precount_kernel<<<NBP, 256, 0, stream>>>(ei_p_dst, ei_q_dst, segt);
    segbase_kernel<<<1, 64, 0, stream>>>(segt, segb, segc);
    partition_kernel<<<NBP, 256, 0, stream>>>(ei_p_src, ei_p_dst, ei_q_src, ei_q_dst, segc, stg);

    sort_kernel<<<SEGW, 1024, 0, stream>>>(segb, segc, stg, srtp, srtq, offp, offq, cnt);

    // aggP first (consumes xe + stg region), then aggQ (writes aggq INTO xe's space)
    aggP_kernel<<<N_LIC / 16, 256, 0, stream>>>(xe, offp, cnt, srtp, aggp);
    aggQ_kernel<<<N_LIC / 16, 256, 0, stream>>>(xc, offq, cnt + N_LIC, srtq, aggq);

    gemm_kernel<<<N_LIC / 64, 256, 0, stream>>>(aggp, aggq, x_lic, Bpk, bias, out);
}

// Round 9
// 380.665 us; speedup vs baseline: 1.0738x; 1.0738x over previous
//
#include <hip/hip_runtime.h>

// Problem constants
#define N_LIC 40000
#define N_EMP 80000
#define N_CON 60000
#define D_EMP 128
#define D_CON 192
#define HDIM  256
#define E_P   1280000
#define E_Q   640000
#define E_T   (E_P + E_Q)

#define NSEG  64            // sub-ranges per relation (625 dst each)
#define SEGW  (2 * NSEG)    // 128 total segments
#define SUBR  (N_LIC / NSEG) // 625 dst per segment

// -------------------- workspace layout (4-byte units) --------------------
// Total ~62.4 MB
#define OFF_AGGP   0                                   // 40000x128 bf16 -> 2,560,000 dw
#define OFF_STG    OFF_AGGP                            // ALIAS: packed-edge staging 1,920,000 dw
#define OFF_XE     (OFF_AGGP + 2560000)                // 80000x128 bf16 -> 5,120,000 dw
#define OFF_AGGQ   OFF_XE                              // ALIAS: aggq reuses xe (xe dead after aggP)
#define OFF_XC     (OFF_XE + 5120000)                  // 60000x192 bf16 -> 5,760,000 dw
#define OFF_BPK    (OFF_XC + 5760000)                  // 256x576 bf16 -> 73,728 dw
#define OFF_BIAS   (OFF_BPK + 73728)                   // 256 f
#define OFF_CNT    (OFF_BIAS + 256)                    // 80000 i (P then Q)
#define OFF_SEGT   (OFF_CNT + 2 * N_LIC)               // 128 i seg totals
#define OFF_SEGB   (OFF_SEGT + 128)                    // 128 i seg bases
#define OFF_SEGC   (OFF_SEGB + 128)                    // 128 i seg cursors
#define OFF_OFFP   (OFF_SEGC + 128)                    // 40000 i
#define OFF_OFFQ   (OFF_OFFP + N_LIC)                  // 40000 i
#define OFF_SRTP   (OFF_OFFQ + N_LIC)                  // 1,280,000 i
#define OFF_SRTQ   (OFF_SRTP + E_P)                    // 640,000 i

typedef short bf16x8 __attribute__((ext_vector_type(8)));
typedef float f32x4 __attribute__((ext_vector_type(4)));

__device__ __forceinline__ ushort f2bf(float f) {
    union { float f; uint u; } v; v.f = f;
    return (ushort)((v.u + 0x7fffu + ((v.u >> 16) & 1u)) >> 16);
}

__device__ __forceinline__ void acc2(uint u, float& lo, float& hi) {
    union { uint u; float f; } a, b;
    a.u = u << 16;
    b.u = u & 0xffff0000u;
    lo += a.f; hi += b.f;
}

__device__ __forceinline__ uint packbf(float lo, float hi) {
    return (uint)f2bf(lo) | ((uint)f2bf(hi) << 16);
}

// -------------------- prep: pack B = [Wl_p; Wl_q; Wr_p+Wr_q] transposed to [n][k] bf16 ----
__global__ void prep_kernel(const float* __restrict__ Wlp, const float* __restrict__ Wlq,
                            const float* __restrict__ Wrp, const float* __restrict__ Wrq,
                            const float* __restrict__ bp, const float* __restrict__ bq,
                            ushort* __restrict__ Bpk, float* __restrict__ bias) {
    int tid = blockIdx.x * 256 + threadIdx.x;
    if (tid < 256 * 576) {
        int n = tid / 576, k = tid - n * 576;
        float v;
        if (k < 128)      v = Wlp[k * 256 + n];
        else if (k < 320) v = Wlq[(k - 128) * 256 + n];
        else              v = Wrp[(k - 320) * 256 + n] + Wrq[(k - 320) * 256 + n];
        Bpk[tid] = f2bf(v);
    } else if (tid < 256 * 576 + 256) {
        int j = tid - 256 * 576;
        bias[j] = bp[j] + bq[j];
    }
}

// -------------------- fused fp32->bf16 conversion of x_emp, x_con --------------------
#define C_XE (N_EMP * 128 / 4)   // 2,560,000 float4s
#define C_XC (N_CON * 192 / 4)   // 2,880,000
__global__ void convert2_kernel(const float* __restrict__ xemp, const float* __restrict__ xcon,
                                ushort* __restrict__ xe, ushort* __restrict__ xc) {
    int tid = blockIdx.x * 256 + threadIdx.x;
    const float* src; ushort* dst; int i;
    if (tid < C_XE) { src = xemp; dst = xe; i = tid; }
    else            { src = xcon; dst = xc; i = tid - C_XE; }
    float4 v = ((const float4*)src)[i];
    uint2 o;
    o.x = packbf(v.x, v.y);
    o.y = packbf(v.z, v.w);
    ((uint2*)dst)[i] = o;
}

// -------------------- pre-count: 128 (rel,subrange) totals, LDS-aggregated --------------------
__global__ __launch_bounds__(256) void precount_kernel(const int* __restrict__ dp,
                                                       const int* __restrict__ dq,
                                                       int* __restrict__ segtot) {
    __shared__ int lc[SEGW];
    int t = threadIdx.x;
    if (t < SEGW) lc[t] = 0;
    __syncthreads();
    int base = blockIdx.x * 2048 + t;
    #pragma unroll
    for (int i = 0; i < 8; i++) {
        int e = base + i * 256;
        if (e < E_T) {
            int d, rel;
            if (e < E_P) { d = __builtin_nontemporal_load(&dp[e]); rel = 0; }
            else         { d = __builtin_nontemporal_load(&dq[e - E_P]); rel = 1; }
            atomicAdd(&lc[rel * NSEG + d / SUBR], 1);
        }
    }
    __syncthreads();
    if (t < SEGW && lc[t] > 0) atomicAdd(&segtot[t], lc[t]);
}

// -------------------- seg bases: exclusive scan of 128 totals --------------------
// Scan order puts all P segments (s<64) in stg[0,E_P), Q segments in [E_P,E_T).
__global__ void segbase_kernel(const int* __restrict__ segtot,
                               int* __restrict__ segbase, int* __restrict__ segcur) {
    if (threadIdx.x == 0) {
        int run = 0;
        for (int i = 0; i < SEGW; i++) {
            segbase[i] = run; segcur[i] = run;
            run += segtot[i];
        }
    }
}

// -------------------- partition: edges -> 128 segments, ALL global writes coalesced ----------
// gfx950 L2 does not write-allocate scattered 4B stores (R4/R6: ~9x write amp regardless of
// affinity). So: sort the block's 2048 edges by segment in LDS, claim per-seg spans, then
// copy out with consecutive threads -> consecutive addresses.
__global__ __launch_bounds__(256) void partition_kernel(const int* __restrict__ sp,
                                                        const int* __restrict__ dp,
                                                        const int* __restrict__ sq,
                                                        const int* __restrict__ dq,
                                                        int* __restrict__ segcur,
                                                        uint* __restrict__ stg) {
    __shared__ int lc[SEGW], inc[SEGW], lb[SEGW], gb[SEGW];
    __shared__ uint srtd[2048];
    __shared__ uchar sid[2048];
    int t = threadIdx.x;
    if (t < SEGW) lc[t] = 0;
    __syncthreads();
    int seg[8], lo[8]; uint pk[8];
    int base = blockIdx.x * 2048 + t;
    #pragma unroll
    for (int i = 0; i < 8; i++) {
        int e = base + i * 256;
        seg[i] = -1;
        if (e < E_T) {
            int d, s, rel;
            if (e < E_P) {
                d = __builtin_nontemporal_load(&dp[e]);
                s = __builtin_nontemporal_load(&sp[e]); rel = 0;
            } else {
                int eq = e - E_P;
                d = __builtin_nontemporal_load(&dq[eq]);
                s = __builtin_nontemporal_load(&sq[eq]); rel = 1;
            }
            int sl = d / SUBR;
            int dl = d - sl * SUBR;
            seg[i] = rel * NSEG + sl;
            pk[i] = ((uint)dl << 17) | (uint)s;
            lo[i] = atomicAdd(&lc[seg[i]], 1);
        }
    }
    __syncthreads();
    if (t < SEGW) inc[t] = lc[t];
    __syncthreads();
    #pragma unroll
    for (int off = 1; off < SEGW; off <<= 1) {
        int v = (t >= off && t < SEGW) ? inc[t - off] : 0;
        __syncthreads();
        if (t < SEGW) inc[t] += v;
        __syncthreads();
    }
    if (t < SEGW) {
        lb[t] = inc[t] - lc[t];
        gb[t] = lc[t] > 0 ? atomicAdd(&segcur[t], lc[t]) : 0;
    }
    __syncthreads();
    #pragma unroll
    for (int i = 0; i < 8; i++) {
        if (seg[i] >= 0) {
            int p = lb[seg[i]] + lo[i];
            srtd[p] = pk[i];
            sid[p] = (uchar)seg[i];
        }
    }
    __syncthreads();
    int tot = inc[SEGW - 1];
    for (int p = t; p < tot; p += 256) {
        int s = sid[p];
        stg[gb[s] + (p - lb[s])] = srtd[p];
    }
}

// -------------------- per-segment in-LDS counting sort -> srt, offs, cnt --------------------
#define LCAP 22528   // 88 KB sorted buffer; P seg mean 20000, sd ~140 -> 18 sigma margin
__global__ __launch_bounds__(1024) void sort_kernel(const int* __restrict__ segbase,
                                                    const int* __restrict__ segcur,
                                                    const uint* __restrict__ stg,
                                                    int* __restrict__ srtp, int* __restrict__ srtq,
                                                    int* __restrict__ offp, int* __restrict__ offq,
                                                    int* __restrict__ cnt) {
    __shared__ int lcnt[SUBR], lcur[SUBR];
    __shared__ int sc[640];
    __shared__ uint buf[LCAP];
    int s = blockIdx.x;
    int rel = s >> 6;
    int beg = segbase[s], end = segcur[s];
    int t = threadIdx.x;
    if (t < SUBR) { lcnt[t] = 0; lcur[t] = 0; }
    __syncthreads();
    for (int idx = beg + t; idx < end; idx += 1024)
        atomicAdd(&lcnt[stg[idx] >> 17], 1);
    __syncthreads();
    if (t < 640) sc[t] = (t < SUBR) ? lcnt[t] : 0;
    __syncthreads();
    #pragma unroll
    for (int off = 1; off < 640; off <<= 1) {
        int v = (t >= off && t < 640) ? sc[t - off] : 0;
        __syncthreads();
        if (t < 640) sc[t] += v;
        __syncthreads();
    }
    int rb = (rel == 0) ? beg : beg - E_P;
    int* srt = (rel == 0) ? srtp : srtq;
    for (int idx = beg + t; idx < end; idx += 1024) {
        uint p = stg[idx];
        int dl = (int)(p >> 17);
        int pos = sc[dl] - lcnt[dl] + atomicAdd(&lcur[dl], 1);
        uint sv = p & 0x1FFFFu;
        if (pos < LCAP) buf[pos] = sv;
        else srt[rb + pos] = (int)sv;   // astronomically rare overflow fallback
    }
    __syncthreads();
    int n = end - beg;
    int m = n < LCAP ? n : LCAP;
    for (int p = t; p < m; p += 1024) srt[rb + p] = (int)buf[p];
    int dbase = (s & (NSEG - 1)) * SUBR;
    int* offs = (rel == 0) ? offp : offq;
    int* cn = (rel == 0) ? cnt : cnt + N_LIC;
    if (t < SUBR) {
        offs[dbase + t] = rb + sc[t] - lcnt[t];
        cn[dbase + t] = lcnt[t];
    }
}

// -------------------- aggregate P: 16 lanes/node, D=128 bf16 in -> bf16 out ------------
__global__ __launch_bounds__(256) void aggP_kernel(const ushort* __restrict__ xe,
                                                   const int* __restrict__ offs,
                                                   const int* __restrict__ cnt,
                                                   const int* __restrict__ sorted,
                                                   ushort* __restrict__ agg) {
    int g = blockIdx.x * 16 + (threadIdx.x >> 4);
    int c = threadIdx.x & 15;
    int beg = offs[g], deg = cnt[g], end = beg + deg;
    float a0=0,a1=0,a2=0,a3=0,a4=0,a5=0,a6=0,a7=0;
    for (int eb = beg; eb < end; eb += 16) {
        int n = end - eb; if (n > 16) n = 16;
        int my = (c < n) ? sorted[eb + c] : 0;
        for (int j = 0; j < n; j++) {
            int s = __shfl(my, j, 16);
            uint4 v = *(const uint4*)(xe + (size_t)s * D_EMP + c * 8);
            acc2(v.x, a0, a1); acc2(v.y, a2, a3);
            acc2(v.z, a4, a5); acc2(v.w, a6, a7);
        }
    }
    float inv = 1.0f / fmaxf((float)deg, 1.0f);
    uint4 o;
    o.x = packbf(a0 * inv, a1 * inv);
    o.y = packbf(a2 * inv, a3 * inv);
    o.z = packbf(a4 * inv, a5 * inv);
    o.w = packbf(a6 * inv, a7 * inv);
    *(uint4*)(agg + (size_t)g * D_EMP + c * 8) = o;
}

// -------------------- aggregate Q: 16 lanes/node, D=192 bf16 in -> bf16 out ------------
__global__ __launch_bounds__(256) void aggQ_kernel(const ushort* __restrict__ xc,
                                                   const int* __restrict__ offs,
                                                   const int* __restrict__ cnt,
                                                   const int* __restrict__ sorted,
                                                   ushort* __restrict__ agg) {
    int g = blockIdx.x * 16 + (threadIdx.x >> 4);
    int c = threadIdx.x & 15;
    int beg = offs[g], deg = cnt[g], end = beg + deg;
    float a0=0,a1=0,a2=0,a3=0,a4=0,a5=0,a6=0,a7=0,a8=0,a9=0,a10=0,a11=0;
    for (int eb = beg; eb < end; eb += 16) {
        int n = end - eb; if (n > 16) n = 16;
        int my = (c < n) ? sorted[eb + c] : 0;
        for (int j = 0; j < n; j++) {
            int s = __shfl(my, j, 16);
            const ushort* row = xc + (size_t)s * D_CON + c * 12;
            uint2 v0 = *(const uint2*)(row + 0);
            uint2 v1 = *(const uint2*)(row + 4);
            uint2 v2 = *(const uint2*)(row + 8);
            acc2(v0.x, a0, a1);  acc2(v0.y, a2, a3);
            acc2(v1.x, a4, a5);  acc2(v1.y, a6, a7);
            acc2(v2.x, a8, a9);  acc2(v2.y, a10, a11);
        }
    }
    float inv = 1.0f / fmaxf((float)deg, 1.0f);
    ushort* o = agg + (size_t)g * D_CON + c * 12;
    uint2 w0, w1, w2;
    w0.x = packbf(a0 * inv, a1 * inv);   w0.y = packbf(a2 * inv, a3 * inv);
    w1.x = packbf(a4 * inv, a5 * inv);   w1.y = packbf(a6 * inv, a7 * inv);
    w2.x = packbf(a8 * inv, a9 * inv);   w2.y = packbf(a10 * inv, a11 * inv);
    *(uint2*)(o + 0) = w0;
    *(uint2*)(o + 4) = w1;
    *(uint2*)(o + 8) = w2;
}

// -------------------- MFMA bf16 GEMM + bias + relu --------------------
// C[40000,256] = relu(0.5*([aggp|aggq|bf16(x_lic)] @ B + bias)); B prepacked [n=256][k=576].
// R8 lesson: LDS-free regressed (scattered per-wave B re-reads, 74KB/wave > L1). R7 lesson:
// LDS-staged version was grid-limited (625 blocks = 2.4/CU, Occupancy 12%). Fix: BM=32 ->
// 1250 blocks ~4.9/CU, ALL resident (LDS 23KB, ~96 VGPR) -> ~20 waves/CU hide the staging
// latency at each barrier. 4 waves, each 32 rows x 64 cols = acc[2][4].
__global__ __launch_bounds__(256) void gemm_kernel(
    const ushort* __restrict__ aggp, const ushort* __restrict__ aggq,
    const float* __restrict__ xlic, const ushort* __restrict__ Bpk,
    const float* __restrict__ bias, float* __restrict__ out)
{
    __shared__ __align__(16) ushort As[32 * 40];   // [m][k], k padded 32->40
    __shared__ __align__(16) ushort Bs[256 * 40];  // [n][k]

    const int t = threadIdx.x;
    const int m0 = blockIdx.x * 32;
    const int lane = t & 63;
    const int wave = t >> 6;
    const int bcol = t >> 2;   // 0..63 (B stage col base)
    const int achk = t & 3;    // 0..3
    const int l15 = lane & 15;
    const int lh  = lane >> 4; // 0..3

    f32x4 acc[2][4];
    #pragma unroll
    for (int i = 0; i < 2; i++)
        #pragma unroll
        for (int j = 0; j < 4; j++)
            acc[i][j] = (f32x4){0.f, 0.f, 0.f, 0.f};

    for (int k0 = 0; k0 < 576; k0 += 32) {
        // stage A tile: 32 rows x 32 k, threads 0..127 (16B each)
        if (t < 128) {
            const int row = t >> 2;
            const int chk = t & 3;
            if (k0 < 320) {
                const ushort* Asrc; int ldA; int ko;
                if (k0 < 128) { Asrc = aggp; ldA = 128; ko = k0; }
                else          { Asrc = aggq; ldA = 192; ko = k0 - 128; }
                const uint4 v = *(const uint4*)(Asrc + (size_t)(m0 + row) * ldA + ko + chk * 8);
                *(uint4*)(As + row * 40 + chk * 8) = v;
            } else {
                const float* src = xlic + (size_t)(m0 + row) * 256 + (k0 - 320) + chk * 8;
                float4 v0 = *(const float4*)(src + 0);
                float4 v1 = *(const float4*)(src + 4);
                uint4 o;
                o.x = packbf(v0.x, v0.y);
                o.y = packbf(v0.z, v0.w);
                o.z = packbf(v1.x, v1.y);
                o.w = packbf(v1.z, v1.w);
                *(uint4*)(As + row * 40 + chk * 8) = o;
            }
        }
        // stage B tile: 256 cols x 32 k (4 x 16B per thread)
        #pragma unroll
        for (int i = 0; i < 4; i++) {
            int col = bcol + i * 64;
            const uint4 v = *(const uint4*)(Bpk + (size_t)col * 576 + k0 + achk * 8);
            *(uint4*)(Bs + col * 40 + achk * 8) = v;
        }
        __syncthreads();

        bf16x8 af[2], bfr[4];
        #pragma unroll
        for (int mt = 0; mt < 2; mt++)
            af[mt] = *(const bf16x8*)(As + (mt * 16 + l15) * 40 + lh * 8);
        #pragma unroll
        for (int nt = 0; nt < 4; nt++)
            bfr[nt] = *(const bf16x8*)(Bs + (wave * 64 + nt * 16 + l15) * 40 + lh * 8);

        #pragma unroll
        for (int mt = 0; mt < 2; mt++)
            #pragma unroll
            for (int nt = 0; nt < 4; nt++)
                acc[mt][nt] = __builtin_amdgcn_mfma_f32_16x16x32_bf16(af[mt], bfr[nt], acc[mt][nt], 0, 0, 0);

        __syncthreads();
    }

    // epilogue: C/D layout col=lane&15, row=(lane>>4)*4+reg
    #pragma unroll
    for (int nt = 0; nt < 4; nt++) {
        int n = wave * 64 + nt * 16 + l15;
        float bv = bias[n];
        #pragma unroll
        for (int mt = 0; mt < 2; mt++) {
            #pragma unroll
            for (int r = 0; r < 4; r++) {
                int m = m0 + mt * 16 + lh * 4 + r;
                float v = 0.5f * (acc[mt][nt][r] + bv);
                out[(size_t)m * 256 + n] = fmaxf(v, 0.f);
            }
        }
    }
}

// -------------------- launch --------------------
extern "C" void kernel_launch(void* const* d_in, const int* in_sizes, int n_in,
                              void* d_out, int out_size, void* d_ws, size_t ws_size,
                              hipStream_t stream) {
    const float* x_lic = (const float*)d_in[0];
    const float* x_emp = (const float*)d_in[1];
    const float* x_con = (const float*)d_in[2];
    const float* Wl_p  = (const float*)d_in[3];
    const float* Wr_p  = (const float*)d_in[4];
    const float* b_p   = (const float*)d_in[5];
    const float* Wl_q  = (const float*)d_in[6];
    const float* Wr_q  = (const float*)d_in[7];
    const float* b_q   = (const float*)d_in[8];
    const int* ei_p_src = (const int*)d_in[9];
    const int* ei_p_dst = (const int*)d_in[10];
    const int* ei_q_src = (const int*)d_in[11];
    const int* ei_q_dst = (const int*)d_in[12];

    float* ws = (float*)d_ws;
    ushort* aggp = (ushort*)(ws + OFF_AGGP);
    ushort* aggq = (ushort*)(ws + OFF_AGGQ);   // aliases xe
    uint*  stg  = (uint*)(ws + OFF_STG);       // aliases aggp
    ushort* xe   = (ushort*)(ws + OFF_XE);
    ushort* xc   = (ushort*)(ws + OFF_XC);
    ushort* Bpk  = (ushort*)(ws + OFF_BPK);
    float* bias  = ws + OFF_BIAS;
    int* cnt  = (int*)(ws + OFF_CNT);
    int* segt = (int*)(ws + OFF_SEGT);
    int* segb = (int*)(ws + OFF_SEGB);
    int* segc = (int*)(ws + OFF_SEGC);
    int* offp = (int*)(ws + OFF_OFFP);
    int* offq = (int*)(ws + OFF_OFFQ);
    int* srtp = (int*)(ws + OFF_SRTP);
    int* srtq = (int*)(ws + OFF_SRTQ);
    float* out = (float*)d_out;

    // only segtot needs zeroing (cnt/offs fully written by sort_kernel)
    hipMemsetAsync(segt, 0, SEGW * sizeof(int), stream);

    prep_kernel<<<(256 * 576 + 256 + 255) / 256, 256, 0, stream>>>(Wl_p, Wl_q, Wr_p, Wr_q, b_p, b_q, Bpk, bias);

    convert2_kernel<<<(C_XE + C_XC) / 256, 256, 0, stream>>>(x_emp, x_con, xe, xc);

    const int NBP = (E_T + 2047) / 2048;   // 938 blocks
    precount_kernel<<<NBP, 256, 0, stream>>>(ei_p_dst, ei_q_dst, segt);
    segbase_kernel<<<1, 64, 0, stream>>>(segt, segb, segc);
    partition_kernel<<<NBP, 256, 0, stream>>>(ei_p_src, ei_p_dst, ei_q_src, ei_q_dst, segc, stg);

    sort_kernel<<<SEGW, 1024, 0, stream>>>(segb, segc, stg, srtp, srtq, offp, offq, cnt);

    // aggP first (consumes xe + stg region), then aggQ (writes aggq INTO xe's space)
    aggP_kernel<<<N_LIC / 16, 256, 0, stream>>>(xe, offp, cnt, srtp, aggp);
    aggQ_kernel<<<N_LIC / 16, 256, 0, stream>>>(xc, offq, cnt + N_LIC, srtq, aggq);

    gemm_kernel<<<N_LIC / 32, 256, 0, stream>>>(aggp, aggq, x_lic, Bpk, bias, out);
}

// Round 10
// 365.653 us; speedup vs baseline: 1.1179x; 1.0411x over previous
//
#include <hip/hip_runtime.h>

// Problem constants
#define N_LIC 40000
#define N_EMP 80000
#define N_CON 60000
#define D_EMP 128
#define D_CON 192
#define HDIM  256
#define E_P   1280000
#define E_Q   640000
#define E_T   (E_P + E_Q)

#define NSEG  64            // sub-ranges per relation (625 dst each)
#define SEGW  (2 * NSEG)    // 128 total segments
#define SUBR  (N_LIC / NSEG) // 625 dst per segment

// -------------------- workspace layout (4-byte units) --------------------
// Total ~62.4 MB
#define OFF_AGGP   0                                   // 40000x128 bf16 -> 2,560,000 dw
#define OFF_STG    OFF_AGGP                            // ALIAS: packed-edge staging 1,920,000 dw
#define OFF_XE     (OFF_AGGP + 2560000)                // 80000x128 bf16 -> 5,120,000 dw
#define OFF_AGGQ   OFF_XE                              // ALIAS: aggq reuses xe (xe dead after aggP)
#define OFF_XC     (OFF_XE + 5120000)                  // 60000x192 bf16 -> 5,760,000 dw
#define OFF_BPK    (OFF_XC + 5760000)                  // 256x576 bf16 -> 73,728 dw
#define OFF_BIAS   (OFF_BPK + 73728)                   // 256 f
#define OFF_CNT    (OFF_BIAS + 256)                    // 80000 i (P then Q)
#define OFF_SEGT   (OFF_CNT + 2 * N_LIC)               // 128 i seg totals
#define OFF_SEGB   (OFF_SEGT + 128)                    // 128 i seg bases
#define OFF_SEGC   (OFF_SEGB + 128)                    // 128 i seg cursors
#define OFF_OFFP   (OFF_SEGC + 128)                    // 40000 i
#define OFF_OFFQ   (OFF_OFFP + N_LIC)                  // 40000 i
#define OFF_SRTP   (OFF_OFFQ + N_LIC)                  // 1,280,000 i
#define OFF_SRTQ   (OFF_SRTP + E_P)                    // 640,000 i

typedef short bf16x8 __attribute__((ext_vector_type(8)));
typedef float f32x4 __attribute__((ext_vector_type(4)));

__device__ __forceinline__ ushort f2bf(float f) {
    union { float f; uint u; } v; v.f = f;
    return (ushort)((v.u + 0x7fffu + ((v.u >> 16) & 1u)) >> 16);
}

__device__ __forceinline__ void acc2(uint u, float& lo, float& hi) {
    union { uint u; float f; } a, b;
    a.u = u << 16;
    b.u = u & 0xffff0000u;
    lo += a.f; hi += b.f;
}

__device__ __forceinline__ uint packbf(float lo, float hi) {
    return (uint)f2bf(lo) | ((uint)f2bf(hi) << 16);
}

// -------------------- prep: pack B = [Wl_p; Wl_q; Wr_p+Wr_q] transposed to [n][k] bf16 ----
__global__ void prep_kernel(const float* __restrict__ Wlp, const float* __restrict__ Wlq,
                            const float* __restrict__ Wrp, const float* __restrict__ Wrq,
                            const float* __restrict__ bp, const float* __restrict__ bq,
                            ushort* __restrict__ Bpk, float* __restrict__ bias) {
    int tid = blockIdx.x * 256 + threadIdx.x;
    if (tid < 256 * 576) {
        int n = tid / 576, k = tid - n * 576;
        float v;
        if (k < 128)      v = Wlp[k * 256 + n];
        else if (k < 320) v = Wlq[(k - 128) * 256 + n];
        else              v = Wrp[(k - 320) * 256 + n] + Wrq[(k - 320) * 256 + n];
        Bpk[tid] = f2bf(v);
    } else if (tid < 256 * 576 + 256) {
        int j = tid - 256 * 576;
        bias[j] = bp[j] + bq[j];
    }
}

// -------------------- fused fp32->bf16 conversion of x_emp, x_con --------------------
#define C_XE (N_EMP * 128 / 4)   // 2,560,000 float4s
#define C_XC (N_CON * 192 / 4)   // 2,880,000
__global__ void convert2_kernel(const float* __restrict__ xemp, const float* __restrict__ xcon,
                                ushort* __restrict__ xe, ushort* __restrict__ xc) {
    int tid = blockIdx.x * 256 + threadIdx.x;
    const float* src; ushort* dst; int i;
    if (tid < C_XE) { src = xemp; dst = xe; i = tid; }
    else            { src = xcon; dst = xc; i = tid - C_XE; }
    float4 v = ((const float4*)src)[i];
    uint2 o;
    o.x = packbf(v.x, v.y);
    o.y = packbf(v.z, v.w);
    ((uint2*)dst)[i] = o;
}

// -------------------- pre-count: 128 (rel,subrange) totals, LDS-aggregated --------------------
__global__ __launch_bounds__(256) void precount_kernel(const int* __restrict__ dp,
                                                       const int* __restrict__ dq,
                                                       int* __restrict__ segtot) {
    __shared__ int lc[SEGW];
    int t = threadIdx.x;
    if (t < SEGW) lc[t] = 0;
    __syncthreads();
    int base = blockIdx.x * 2048 + t;
    #pragma unroll
    for (int i = 0; i < 8; i++) {
        int e = base + i * 256;
        if (e < E_T) {
            int d, rel;
            if (e < E_P) { d = __builtin_nontemporal_load(&dp[e]); rel = 0; }
            else         { d = __builtin_nontemporal_load(&dq[e - E_P]); rel = 1; }
            atomicAdd(&lc[rel * NSEG + d / SUBR], 1);
        }
    }
    __syncthreads();
    if (t < SEGW && lc[t] > 0) atomicAdd(&segtot[t], lc[t]);
}

// -------------------- seg bases: exclusive scan of 128 totals --------------------
__global__ void segbase_kernel(const int* __restrict__ segtot,
                               int* __restrict__ segbase, int* __restrict__ segcur) {
    if (threadIdx.x == 0) {
        int run = 0;
        for (int i = 0; i < SEGW; i++) {
            segbase[i] = run; segcur[i] = run;
            run += segtot[i];
        }
    }
}

// -------------------- partition: edges -> 128 segments, ALL global writes coalesced ----------
__global__ __launch_bounds__(256) void partition_kernel(const int* __restrict__ sp,
                                                        const int* __restrict__ dp,
                                                        const int* __restrict__ sq,
                                                        const int* __restrict__ dq,
                                                        int* __restrict__ segcur,
                                                        uint* __restrict__ stg) {
    __shared__ int lc[SEGW], inc[SEGW], lb[SEGW], gb[SEGW];
    __shared__ uint srtd[2048];
    __shared__ uchar sid[2048];
    int t = threadIdx.x;
    if (t < SEGW) lc[t] = 0;
    __syncthreads();
    int seg[8], lo[8]; uint pk[8];
    int base = blockIdx.x * 2048 + t;
    #pragma unroll
    for (int i = 0; i < 8; i++) {
        int e = base + i * 256;
        seg[i] = -1;
        if (e < E_T) {
            int d, s, rel;
            if (e < E_P) {
                d = __builtin_nontemporal_load(&dp[e]);
                s = __builtin_nontemporal_load(&sp[e]); rel = 0;
            } else {
                int eq = e - E_P;
                d = __builtin_nontemporal_load(&dq[eq]);
                s = __builtin_nontemporal_load(&sq[eq]); rel = 1;
            }
            int sl = d / SUBR;
            int dl = d - sl * SUBR;
            seg[i] = rel * NSEG + sl;
            pk[i] = ((uint)dl << 17) | (uint)s;
            lo[i] = atomicAdd(&lc[seg[i]], 1);
        }
    }
    __syncthreads();
    if (t < SEGW) inc[t] = lc[t];
    __syncthreads();
    #pragma unroll
    for (int off = 1; off < SEGW; off <<= 1) {
        int v = (t >= off && t < SEGW) ? inc[t - off] : 0;
        __syncthreads();
        if (t < SEGW) inc[t] += v;
        __syncthreads();
    }
    if (t < SEGW) {
        lb[t] = inc[t] - lc[t];
        gb[t] = lc[t] > 0 ? atomicAdd(&segcur[t], lc[t]) : 0;
    }
    __syncthreads();
    #pragma unroll
    for (int i = 0; i < 8; i++) {
        if (seg[i] >= 0) {
            int p = lb[seg[i]] + lo[i];
            srtd[p] = pk[i];
            sid[p] = (uchar)seg[i];
        }
    }
    __syncthreads();
    int tot = inc[SEGW - 1];
    for (int p = t; p < tot; p += 256) {
        int s = sid[p];
        stg[gb[s] + (p - lb[s])] = srtd[p];
    }
}

// -------------------- per-segment in-LDS counting sort -> srt, offs, cnt --------------------
#define LCAP 22528   // 88 KB sorted buffer; P seg mean 20000, sd ~140 -> 18 sigma margin
__global__ __launch_bounds__(1024) void sort_kernel(const int* __restrict__ segbase,
                                                    const int* __restrict__ segcur,
                                                    const uint* __restrict__ stg,
                                                    int* __restrict__ srtp, int* __restrict__ srtq,
                                                    int* __restrict__ offp, int* __restrict__ offq,
                                                    int* __restrict__ cnt) {
    __shared__ int lcnt[SUBR], lcur[SUBR];
    __shared__ int sc[640];
    __shared__ uint buf[LCAP];
    int s = blockIdx.x;
    int rel = s >> 6;
    int beg = segbase[s], end = segcur[s];
    int t = threadIdx.x;
    if (t < SUBR) { lcnt[t] = 0; lcur[t] = 0; }
    __syncthreads();
    for (int idx = beg + t; idx < end; idx += 1024)
        atomicAdd(&lcnt[stg[idx] >> 17], 1);
    __syncthreads();
    if (t < 640) sc[t] = (t < SUBR) ? lcnt[t] : 0;
    __syncthreads();
    #pragma unroll
    for (int off = 1; off < 640; off <<= 1) {
        int v = (t >= off && t < 640) ? sc[t - off] : 0;
        __syncthreads();
        if (t < 640) sc[t] += v;
        __syncthreads();
    }
    int rb = (rel == 0) ? beg : beg - E_P;
    int* srt = (rel == 0) ? srtp : srtq;
    for (int idx = beg + t; idx < end; idx += 1024) {
        uint p = stg[idx];
        int dl = (int)(p >> 17);
        int pos = sc[dl] - lcnt[dl] + atomicAdd(&lcur[dl], 1);
        uint sv = p & 0x1FFFFu;
        if (pos < LCAP) buf[pos] = sv;
        else srt[rb + pos] = (int)sv;   // astronomically rare overflow fallback
    }
    __syncthreads();
    int n = end - beg;
    int m = n < LCAP ? n : LCAP;
    for (int p = t; p < m; p += 1024) srt[rb + p] = (int)buf[p];
    int dbase = (s & (NSEG - 1)) * SUBR;
    int* offs = (rel == 0) ? offp : offq;
    int* cn = (rel == 0) ? cnt : cnt + N_LIC;
    if (t < SUBR) {
        offs[dbase + t] = rb + sc[t] - lcnt[t];
        cn[dbase + t] = lcnt[t];
    }
}

// -------------------- aggregate P: 16 lanes/node, D=128 bf16 in -> bf16 out ------------
__global__ __launch_bounds__(256) void aggP_kernel(const ushort* __restrict__ xe,
                                                   const int* __restrict__ offs,
                                                   const int* __restrict__ cnt,
                                                   const int* __restrict__ sorted,
                                                   ushort* __restrict__ agg) {
    int g = blockIdx.x * 16 + (threadIdx.x >> 4);
    int c = threadIdx.x & 15;
    int beg = offs[g], deg = cnt[g], end = beg + deg;
    float a0=0,a1=0,a2=0,a3=0,a4=0,a5=0,a6=0,a7=0;
    for (int eb = beg; eb < end; eb += 16) {
        int n = end - eb; if (n > 16) n = 16;
        int my = (c < n) ? sorted[eb + c] : 0;
        for (int j = 0; j < n; j++) {
            int s = __shfl(my, j, 16);
            uint4 v = *(const uint4*)(xe + (size_t)s * D_EMP + c * 8);
            acc2(v.x, a0, a1); acc2(v.y, a2, a3);
            acc2(v.z, a4, a5); acc2(v.w, a6, a7);
        }
    }
    float inv = 1.0f / fmaxf((float)deg, 1.0f);
    uint4 o;
    o.x = packbf(a0 * inv, a1 * inv);
    o.y = packbf(a2 * inv, a3 * inv);
    o.z = packbf(a4 * inv, a5 * inv);
    o.w = packbf(a6 * inv, a7 * inv);
    *(uint4*)(agg + (size_t)g * D_EMP + c * 8) = o;
}

// -------------------- aggregate Q: 16 lanes/node, D=192 bf16 in -> bf16 out ------------
__global__ __launch_bounds__(256) void aggQ_kernel(const ushort* __restrict__ xc,
                                                   const int* __restrict__ offs,
                                                   const int* __restrict__ cnt,
                                                   const int* __restrict__ sorted,
                                                   ushort* __restrict__ agg) {
    int g = blockIdx.x * 16 + (threadIdx.x >> 4);
    int c = threadIdx.x & 15;
    int beg = offs[g], deg = cnt[g], end = beg + deg;
    float a0=0,a1=0,a2=0,a3=0,a4=0,a5=0,a6=0,a7=0,a8=0,a9=0,a10=0,a11=0;
    for (int eb = beg; eb < end; eb += 16) {
        int n = end - eb; if (n > 16) n = 16;
        int my = (c < n) ? sorted[eb + c] : 0;
        for (int j = 0; j < n; j++) {
            int s = __shfl(my, j, 16);
            const ushort* row = xc + (size_t)s * D_CON + c * 12;
            uint2 v0 = *(const uint2*)(row + 0);
            uint2 v1 = *(const uint2*)(row + 4);
            uint2 v2 = *(const uint2*)(row + 8);
            acc2(v0.x, a0, a1);  acc2(v0.y, a2, a3);
            acc2(v1.x, a4, a5);  acc2(v1.y, a6, a7);
            acc2(v2.x, a8, a9);  acc2(v2.y, a10, a11);
        }
    }
    float inv = 1.0f / fmaxf((float)deg, 1.0f);
    ushort* o = agg + (size_t)g * D_CON + c * 12;
    uint2 w0, w1, w2;
    w0.x = packbf(a0 * inv, a1 * inv);   w0.y = packbf(a2 * inv, a3 * inv);
    w1.x = packbf(a4 * inv, a5 * inv);   w1.y = packbf(a6 * inv, a7 * inv);
    w2.x = packbf(a8 * inv, a9 * inv);   w2.y = packbf(a10 * inv, a11 * inv);
    *(uint2*)(o + 0) = w0;
    *(uint2*)(o + 4) = w1;
    *(uint2*)(o + 8) = w2;
}

// -------------------- MFMA bf16 GEMM + bias + relu (double-buffered pipeline) --------------------
// C[40000,256] = relu(0.5*([aggp|aggq|bf16(x_lic)] @ B + bias)); B prepacked [n=256][k=576].
// R7/R9 lesson: stage->barrier->MFMA->barrier exposes L2 latency 18x/block (MfmaUtil ~7%).
// Fix: BM=64 (R7 geometry, fewer staging duplicates) + dbuf LDS + register prefetch:
// per iter: issue next-tile global loads -> compute current from LDS -> write prefetch regs
// into the OTHER buffer -> ONE barrier. Load latency hides under 16 MFMA + ds_reads.
__global__ __launch_bounds__(256) void gemm_kernel(
    const ushort* __restrict__ aggp, const ushort* __restrict__ aggq,
    const float* __restrict__ xlic, const ushort* __restrict__ Bpk,
    const float* __restrict__ bias, float* __restrict__ out)
{
    __shared__ __align__(16) ushort As[2][64 * 40];   // [m][k], k padded 32->40
    __shared__ __align__(16) ushort Bs[2][256 * 40];  // [n][k]

    const int t = threadIdx.x;
    const int m0 = blockIdx.x * 64;
    const int lane = t & 63;
    const int wave = t >> 6;
    const int arow = t >> 2;   // 0..63
    const int achk = t & 3;    // 0..3
    const int l15 = lane & 15;
    const int lh  = lane >> 4; // 0..3

    f32x4 acc[4][4];
    #pragma unroll
    for (int i = 0; i < 4; i++)
        #pragma unroll
        for (int j = 0; j < 4; j++)
            acc[i][j] = (f32x4){0.f, 0.f, 0.f, 0.f};

    uint4 pb0, pb1, pb2, pb3, pa0, pa1;

    // ---- prefetch tile k0 into regs ----
    #define REG_LOAD(k0)                                                                     \
    {                                                                                        \
        pb0 = *(const uint4*)(Bpk + (size_t)(arow +   0) * 576 + (k0) + achk * 8);           \
        pb1 = *(const uint4*)(Bpk + (size_t)(arow +  64) * 576 + (k0) + achk * 8);           \
        pb2 = *(const uint4*)(Bpk + (size_t)(arow + 128) * 576 + (k0) + achk * 8);           \
        pb3 = *(const uint4*)(Bpk + (size_t)(arow + 192) * 576 + (k0) + achk * 8);           \
        if ((k0) < 128) {                                                                    \
            pa0 = *(const uint4*)(aggp + (size_t)(m0 + arow) * 128 + (k0) + achk * 8);       \
        } else if ((k0) < 320) {                                                             \
            pa0 = *(const uint4*)(aggq + (size_t)(m0 + arow) * 192 + ((k0) - 128) + achk * 8); \
        } else {                                                                             \
            const float* src_ = xlic + (size_t)(m0 + arow) * 256 + ((k0) - 320) + achk * 8;  \
            pa0 = *(const uint4*)(src_ + 0);                                                 \
            pa1 = *(const uint4*)(src_ + 4);                                                 \
        }                                                                                    \
    }

    // ---- write prefetch regs into LDS buffer b for tile k0 ----
    #define LDS_WRITE(b, k0)                                                                 \
    {                                                                                        \
        uint4 aw;                                                                            \
        if ((k0) < 320) aw = pa0;                                                            \
        else {                                                                               \
            union { uint4 u; float f[4]; } c0, c1;                                           \
            c0.u = pa0; c1.u = pa1;                                                          \
            aw.x = packbf(c0.f[0], c0.f[1]);                                                 \
            aw.y = packbf(c0.f[2], c0.f[3]);                                                 \
            aw.z = packbf(c1.f[0], c1.f[1]);                                                 \
            aw.w = packbf(c1.f[2], c1.f[3]);                                                 \
        }                                                                                    \
        *(uint4*)(&As[b][arow * 40 + achk * 8]) = aw;                                        \
        *(uint4*)(&Bs[b][(arow +   0) * 40 + achk * 8]) = pb0;                               \
        *(uint4*)(&Bs[b][(arow +  64) * 40 + achk * 8]) = pb1;                               \
        *(uint4*)(&Bs[b][(arow + 128) * 40 + achk * 8]) = pb2;                               \
        *(uint4*)(&Bs[b][(arow + 192) * 40 + achk * 8]) = pb3;                               \
    }

    // ---- compute from LDS buffer b ----
    #define COMPUTE(b)                                                                       \
    {                                                                                        \
        bf16x8 af[4], bfr[4];                                                                \
        _Pragma("unroll")                                                                    \
        for (int mt = 0; mt < 4; mt++)                                                       \
            af[mt] = *(const bf16x8*)(&As[b][(mt * 16 + l15) * 40 + lh * 8]);                \
        _Pragma("unroll")                                                                    \
        for (int nt = 0; nt < 4; nt++)                                                       \
            bfr[nt] = *(const bf16x8*)(&Bs[b][(wave * 64 + nt * 16 + l15) * 40 + lh * 8]);   \
        _Pragma("unroll")                                                                    \
        for (int mt = 0; mt < 4; mt++)                                                       \
            _Pragma("unroll")                                                                \
            for (int nt = 0; nt < 4; nt++)                                                   \
                acc[mt][nt] = __builtin_amdgcn_mfma_f32_16x16x32_bf16(af[mt], bfr[nt], acc[mt][nt], 0, 0, 0); \
    }

    // prologue: tile 0 -> buf 0
    REG_LOAD(0);
    LDS_WRITE(0, 0);
    __syncthreads();

    int cur = 0;
    for (int k0 = 32; k0 < 576; k0 += 32) {
        REG_LOAD(k0);          // issue next tile's loads (latency hidden under COMPUTE)
        COMPUTE(cur);          // current tile from LDS
        LDS_WRITE(cur ^ 1, k0);// write next tile into the other buffer (no race w/ readers)
        __syncthreads();       // single barrier: next tile visible to all
        cur ^= 1;
    }
    COMPUTE(cur);              // last tile

    // epilogue: C/D layout col=lane&15, row=(lane>>4)*4+reg
    #pragma unroll
    for (int nt = 0; nt < 4; nt++) {
        int n = wave * 64 + nt * 16 + l15;
        float bv = bias[n];
        #pragma unroll
        for (int mt = 0; mt < 4; mt++) {
            #pragma unroll
            for (int r = 0; r < 4; r++) {
                int m = m0 + mt * 16 + lh * 4 + r;
                float v = 0.5f * (acc[mt][nt][r] + bv);
                out[(size_t)m * 256 + n] = fmaxf(v, 0.f);
            }
        }
    }
    #undef REG_LOAD
    #undef LDS_WRITE
    #undef COMPUTE
}

// -------------------- launch --------------------
extern "C" void kernel_launch(void* const* d_in, const int* in_sizes, int n_in,
                              void* d_out, int out_size, void* d_ws, size_t ws_size,
                              hipStream_t stream) {
    const float* x_lic = (const float*)d_in[0];
    const float* x_emp = (const float*)d_in[1];
    const float* x_con = (const float*)d_in[2];
    const float* Wl_p  = (const float*)d_in[3];
    const float* Wr_p  = (const float*)d_in[4];
    const float* b_p   = (const float*)d_in[5];
    const float* Wl_q  = (const float*)d_in[6];
    const float* Wr_q  = (const float*)d_in[7];
    const float* b_q   = (const float*)d_in[8];
    const int* ei_p_src = (const int*)d_in[9];
    const int* ei_p_dst = (const int*)d_in[10];
    const int* ei_q_src = (const int*)d_in[11];
    const int* ei_q_dst = (const int*)d_in[12];

    float* ws = (float*)d_ws;
    ushort* aggp = (ushort*)(ws + OFF_AGGP);
    ushort* aggq = (ushort*)(ws + OFF_AGGQ);   // aliases xe
    uint*  stg  = (uint*)(ws + OFF_STG);       // aliases aggp
    ushort* xe   = (ushort*)(ws + OFF_XE);
    ushort* xc   = (ushort*)(ws + OFF_XC);
    ushort* Bpk  = (ushort*)(ws + OFF_BPK);
    float* bias  = ws + OFF_BIAS;
    int* cnt  = (int*)(ws + OFF_CNT);
    int* segt = (int*)(ws + OFF_SEGT);
    int* segb = (int*)(ws + OFF_SEGB);
    int* segc = (int*)(ws + OFF_SEGC);
    int* offp = (int*)(ws + OFF_OFFP);
    int* offq = (int*)(ws + OFF_OFFQ);
    int* srtp = (int*)(ws + OFF_SRTP);
    int* srtq = (int*)(ws + OFF_SRTQ);
    float* out = (float*)d_out;

    // only segtot needs zeroing (cnt/offs fully written by sort_kernel)
    hipMemsetAsync(segt, 0, SEGW * sizeof(int), stream);

    prep_kernel<<<(256 * 576 + 256 + 255) / 256, 256, 0, stream>>>(Wl_p, Wl_q, Wr_p, Wr_q, b_p, b_q, Bpk, bias);

    convert2_kernel<<<(C_XE + C_XC) / 256, 256, 0, stream>>>(x_emp, x_con, xe, xc);

    const int NBP = (E_T + 2047) / 2048;   // 938 blocks
    precount_kernel<<<NBP, 256, 0, stream>>>(ei_p_dst, ei_q_dst, segt);
    segbase_kernel<<<1, 64, 0, stream>>>(segt, segb, segc);
    partition_kernel<<<NBP, 256, 0, stream>>>(ei_p_src, ei_p_dst, ei_q_src, ei_q_dst, segc, stg);

    sort_kernel<<<SEGW, 1024, 0, stream>>>(segb, segc, stg, srtp, srtq, offp, offq, cnt);

    // aggP first (consumes xe + stg region), then aggQ (writes aggq INTO xe's space)
    aggP_kernel<<<N_LIC / 16, 256, 0, stream>>>(xe, offp, cnt, srtp, aggp);
    aggQ_kernel<<<N_LIC / 16, 256, 0, stream>>>(xc, offq, cnt + N_LIC, srtq, aggq);

    gemm_kernel<<<N_LIC / 64, 256, 0, stream>>>(aggp, aggq, x_lic, Bpk, bias, out);
}

// Round 11
// 354.642 us; speedup vs baseline: 1.1526x; 1.0310x over previous
//
#include <hip/hip_runtime.h>

// Problem constants
#define N_LIC 40000
#define N_EMP 80000
#define N_CON 60000
#define D_EMP 128
#define D_CON 192
#define HDIM  256
#define E_P   1280000
#define E_Q   640000
#define E_T   (E_P + E_Q)

#define NSEG  64            // sub-ranges per relation (625 dst each)
#define SEGW  (2 * NSEG)    // 128 total segments
#define SUBR  (N_LIC / NSEG) // 625 dst per segment
#define NBPRE ((E_T + 2047) / 2048)   // 938 precount/partition blocks

// -------------------- workspace layout (4-byte units) --------------------
// Total ~62.4 MB
#define OFF_AGGP   0                                   // 40000x128 bf16 -> 2,560,000 dw
#define OFF_STG    OFF_AGGP                            // ALIAS: packed-edge staging 1,920,000 dw
#define OFF_XE     (OFF_AGGP + 2560000)                // 80000x128 bf16 -> 5,120,000 dw
#define OFF_AGGQ   OFF_XE                              // ALIAS: aggq reuses xe (xe dead after aggP)
#define OFF_XC     (OFF_XE + 5120000)                  // 60000x192 bf16 -> 5,760,000 dw
#define OFF_BPK    (OFF_XC + 5760000)                  // 256x576 bf16 -> 73,728 dw
#define OFF_BIAS   (OFF_BPK + 73728)                   // 256 f
#define OFF_CNT    (OFF_BIAS + 256)                    // 80000 i (P then Q)
#define OFF_SEGT   (OFF_CNT + 2 * N_LIC)               // 128 i seg totals
#define OFF_SEGB   (OFF_SEGT + 128)                    // 128 i seg bases
#define OFF_SEGC   (OFF_SEGB + 128)                    // 128 i seg cursors
#define OFF_OFFP   (OFF_SEGC + 128)                    // 40000 i
#define OFF_OFFQ   (OFF_OFFP + N_LIC)                  // 40000 i
#define OFF_SRTP   (OFF_OFFQ + N_LIC)                  // 1,280,000 i
#define OFF_SRTQ   (OFF_SRTP + E_P)                    // 640,000 i

typedef short bf16x8 __attribute__((ext_vector_type(8)));
typedef float f32x4 __attribute__((ext_vector_type(4)));

__device__ __forceinline__ ushort f2bf(float f) {
    union { float f; uint u; } v; v.f = f;
    return (ushort)((v.u + 0x7fffu + ((v.u >> 16) & 1u)) >> 16);
}

__device__ __forceinline__ void acc2(uint u, float& lo, float& hi) {
    union { uint u; float f; } a, b;
    a.u = u << 16;
    b.u = u & 0xffff0000u;
    lo += a.f; hi += b.f;
}

__device__ __forceinline__ uint packbf(float lo, float hi) {
    return (uint)f2bf(lo) | ((uint)f2bf(hi) << 16);
}

// -------------------- prep: pack B = [Wl_p; Wl_q; Wr_p+Wr_q] transposed to [n][k] bf16 ----
__global__ void prep_kernel(const float* __restrict__ Wlp, const float* __restrict__ Wlq,
                            const float* __restrict__ Wrp, const float* __restrict__ Wrq,
                            const float* __restrict__ bp, const float* __restrict__ bq,
                            ushort* __restrict__ Bpk, float* __restrict__ bias) {
    int tid = blockIdx.x * 256 + threadIdx.x;
    if (tid < 256 * 576) {
        int n = tid / 576, k = tid - n * 576;
        float v;
        if (k < 128)      v = Wlp[k * 256 + n];
        else if (k < 320) v = Wlq[(k - 128) * 256 + n];
        else              v = Wrp[(k - 320) * 256 + n] + Wrq[(k - 320) * 256 + n];
        Bpk[tid] = f2bf(v);
    } else if (tid < 256 * 576 + 256) {
        int j = tid - 256 * 576;
        bias[j] = bp[j] + bq[j];
    }
}

// -------------------- fused: x_emp/x_con fp32->bf16 convert  ||  seg pre-count --------------------
#define C_XE (N_EMP * 128 / 4)   // 2,560,000 float4s
#define C_XC (N_CON * 192 / 4)   // 2,880,000
__global__ __launch_bounds__(256) void conv_pre_kernel(
        const float* __restrict__ xemp, const float* __restrict__ xcon,
        ushort* __restrict__ xe, ushort* __restrict__ xc,
        const int* __restrict__ dp, const int* __restrict__ dq,
        int* __restrict__ segtot) {
    __shared__ int lc[SEGW];
    int b = blockIdx.x;
    int t = threadIdx.x;
    if (b < NBPRE) {
        if (t < SEGW) lc[t] = 0;
        __syncthreads();
        int base = b * 2048 + t;
        #pragma unroll
        for (int i = 0; i < 8; i++) {
            int e = base + i * 256;
            if (e < E_T) {
                int d, rel;
                if (e < E_P) { d = __builtin_nontemporal_load(&dp[e]); rel = 0; }
                else         { d = __builtin_nontemporal_load(&dq[e - E_P]); rel = 1; }
                atomicAdd(&lc[rel * NSEG + d / SUBR], 1);
            }
        }
        __syncthreads();
        if (t < SEGW && lc[t] > 0) atomicAdd(&segtot[t], lc[t]);
    } else {
        int tid = (b - NBPRE) * 256 + t;
        const float* src; ushort* dst; int i;
        if (tid < C_XE) { src = xemp; dst = xe; i = tid; }
        else            { src = xcon; dst = xc; i = tid - C_XE; }
        float4 v = ((const float4*)src)[i];
        uint2 o;
        o.x = packbf(v.x, v.y);
        o.y = packbf(v.z, v.w);
        ((uint2*)dst)[i] = o;
    }
}

// -------------------- seg bases: exclusive scan of 128 totals --------------------
__global__ void segbase_kernel(const int* __restrict__ segtot,
                               int* __restrict__ segbase, int* __restrict__ segcur) {
    if (threadIdx.x == 0) {
        int run = 0;
        for (int i = 0; i < SEGW; i++) {
            segbase[i] = run; segcur[i] = run;
            run += segtot[i];
        }
    }
}

// -------------------- partition: edges -> 128 segments, ALL global writes coalesced ----------
__global__ __launch_bounds__(256) void partition_kernel(const int* __restrict__ sp,
                                                        const int* __restrict__ dp,
                                                        const int* __restrict__ sq,
                                                        const int* __restrict__ dq,
                                                        int* __restrict__ segcur,
                                                        uint* __restrict__ stg) {
    __shared__ int lc[SEGW], inc[SEGW], lb[SEGW], gb[SEGW];
    __shared__ uint srtd[2048];
    __shared__ uchar sid[2048];
    int t = threadIdx.x;
    if (t < SEGW) lc[t] = 0;
    __syncthreads();
    int seg[8], lo[8]; uint pk[8];
    int base = blockIdx.x * 2048 + t;
    #pragma unroll
    for (int i = 0; i < 8; i++) {
        int e = base + i * 256;
        seg[i] = -1;
        if (e < E_T) {
            int d, s, rel;
            if (e < E_P) {
                d = __builtin_nontemporal_load(&dp[e]);
                s = __builtin_nontemporal_load(&sp[e]); rel = 0;
            } else {
                int eq = e - E_P;
                d = __builtin_nontemporal_load(&dq[eq]);
                s = __builtin_nontemporal_load(&sq[eq]); rel = 1;
            }
            int sl = d / SUBR;
            int dl = d - sl * SUBR;
            seg[i] = rel * NSEG + sl;
            pk[i] = ((uint)dl << 17) | (uint)s;
            lo[i] = atomicAdd(&lc[seg[i]], 1);
        }
    }
    __syncthreads();
    if (t < SEGW) inc[t] = lc[t];
    __syncthreads();
    #pragma unroll
    for (int off = 1; off < SEGW; off <<= 1) {
        int v = (t >= off && t < SEGW) ? inc[t - off] : 0;
        __syncthreads();
        if (t < SEGW) inc[t] += v;
        __syncthreads();
    }
    if (t < SEGW) {
        lb[t] = inc[t] - lc[t];
        gb[t] = lc[t] > 0 ? atomicAdd(&segcur[t], lc[t]) : 0;
    }
    __syncthreads();
    #pragma unroll
    for (int i = 0; i < 8; i++) {
        if (seg[i] >= 0) {
            int p = lb[seg[i]] + lo[i];
            srtd[p] = pk[i];
            sid[p] = (uchar)seg[i];
        }
    }
    __syncthreads();
    int tot = inc[SEGW - 1];
    for (int p = t; p < tot; p += 256) {
        int s = sid[p];
        stg[gb[s] + (p - lb[s])] = srtd[p];
    }
}

// -------------------- per-segment in-LDS counting sort -> srt, offs, cnt --------------------
#define LCAP 22528
__global__ __launch_bounds__(1024) void sort_kernel(const int* __restrict__ segbase,
                                                    const int* __restrict__ segcur,
                                                    const uint* __restrict__ stg,
                                                    int* __restrict__ srtp, int* __restrict__ srtq,
                                                    int* __restrict__ offp, int* __restrict__ offq,
                                                    int* __restrict__ cnt) {
    __shared__ int lcnt[SUBR], lcur[SUBR];
    __shared__ int sc[640];
    __shared__ uint buf[LCAP];
    int s = blockIdx.x;
    int rel = s >> 6;
    int beg = segbase[s], end = segcur[s];
    int t = threadIdx.x;
    if (t < SUBR) { lcnt[t] = 0; lcur[t] = 0; }
    __syncthreads();
    for (int idx = beg + t; idx < end; idx += 1024)
        atomicAdd(&lcnt[stg[idx] >> 17], 1);
    __syncthreads();
    if (t < 640) sc[t] = (t < SUBR) ? lcnt[t] : 0;
    __syncthreads();
    #pragma unroll
    for (int off = 1; off < 640; off <<= 1) {
        int v = (t >= off && t < 640) ? sc[t - off] : 0;
        __syncthreads();
        if (t < 640) sc[t] += v;
        __syncthreads();
    }
    int rb = (rel == 0) ? beg : beg - E_P;
    int* srt = (rel == 0) ? srtp : srtq;
    for (int idx = beg + t; idx < end; idx += 1024) {
        uint p = stg[idx];
        int dl = (int)(p >> 17);
        int pos = sc[dl] - lcnt[dl] + atomicAdd(&lcur[dl], 1);
        uint sv = p & 0x1FFFFu;
        if (pos < LCAP) buf[pos] = sv;
        else srt[rb + pos] = (int)sv;
    }
    __syncthreads();
    int n = end - beg;
    int m = n < LCAP ? n : LCAP;
    for (int p = t; p < m; p += 1024) srt[rb + p] = (int)buf[p];
    int dbase = (s & (NSEG - 1)) * SUBR;
    int* offs = (rel == 0) ? offp : offq;
    int* cn = (rel == 0) ? cnt : cnt + N_LIC;
    if (t < SUBR) {
        offs[dbase + t] = rb + sc[t] - lcnt[t];
        cn[dbase + t] = lcnt[t];
    }
}

// -------------------- aggregate P: 16 lanes/node, UNROLLED gather (MLP fix) ------------
// R10 diagnosis: gather is miss-latency-bound (2.75 TB/s, VALUBusy 21%); traffic is at the
// per-XCD structural minimum. Full-chunk path with unrolled inner loop puts 16 independent
// row loads in flight per lane group (VGPR=16 had huge headroom).
__global__ __launch_bounds__(256) void aggP_kernel(const ushort* __restrict__ xe,
                                                   const int* __restrict__ offs,
                                                   const int* __restrict__ cnt,
                                                   const int* __restrict__ sorted,
                                                   ushort* __restrict__ agg) {
    int g = blockIdx.x * 16 + (threadIdx.x >> 4);
    int c = threadIdx.x & 15;
    int beg = offs[g], deg = cnt[g], end = beg + deg;
    float a0=0,a1=0,a2=0,a3=0,a4=0,a5=0,a6=0,a7=0;
    int eb = beg;
    for (; eb + 16 <= end; eb += 16) {
        int my = sorted[eb + c];
        #pragma unroll
        for (int j = 0; j < 16; j++) {
            int s = __shfl(my, j, 16);
            uint4 v = *(const uint4*)(xe + (size_t)s * D_EMP + c * 8);
            acc2(v.x, a0, a1); acc2(v.y, a2, a3);
            acc2(v.z, a4, a5); acc2(v.w, a6, a7);
        }
    }
    int n = end - eb;
    if (n > 0) {
        int my = (c < n) ? sorted[eb + c] : 0;
        for (int j = 0; j < n; j++) {
            int s = __shfl(my, j, 16);
            uint4 v = *(const uint4*)(xe + (size_t)s * D_EMP + c * 8);
            acc2(v.x, a0, a1); acc2(v.y, a2, a3);
            acc2(v.z, a4, a5); acc2(v.w, a6, a7);
        }
    }
    float inv = 1.0f / fmaxf((float)deg, 1.0f);
    uint4 o;
    o.x = packbf(a0 * inv, a1 * inv);
    o.y = packbf(a2 * inv, a3 * inv);
    o.z = packbf(a4 * inv, a5 * inv);
    o.w = packbf(a6 * inv, a7 * inv);
    *(uint4*)(agg + (size_t)g * D_EMP + c * 8) = o;
}

// -------------------- aggregate Q: 16 lanes/node, UNROLLED gather ------------
__global__ __launch_bounds__(256) void aggQ_kernel(const ushort* __restrict__ xc,
                                                   const int* __restrict__ offs,
                                                   const int* __restrict__ cnt,
                                                   const int* __restrict__ sorted,
                                                   ushort* __restrict__ agg) {
    int g = blockIdx.x * 16 + (threadIdx.x >> 4);
    int c = threadIdx.x & 15;
    int beg = offs[g], deg = cnt[g], end = beg + deg;
    float a0=0,a1=0,a2=0,a3=0,a4=0,a5=0,a6=0,a7=0,a8=0,a9=0,a10=0,a11=0;
    int eb = beg;
    for (; eb + 16 <= end; eb += 16) {
        int my = sorted[eb + c];
        #pragma unroll 8
        for (int j = 0; j < 16; j++) {
            int s = __shfl(my, j, 16);
            const ushort* row = xc + (size_t)s * D_CON + c * 12;
            uint2 v0 = *(const uint2*)(row + 0);
            uint2 v1 = *(const uint2*)(row + 4);
            uint2 v2 = *(const uint2*)(row + 8);
            acc2(v0.x, a0, a1);  acc2(v0.y, a2, a3);
            acc2(v1.x, a4, a5);  acc2(v1.y, a6, a7);
            acc2(v2.x, a8, a9);  acc2(v2.y, a10, a11);
        }
    }
    int n = end - eb;
    if (n > 0) {
        int my = (c < n) ? sorted[eb + c] : 0;
        for (int j = 0; j < n; j++) {
            int s = __shfl(my, j, 16);
            const ushort* row = xc + (size_t)s * D_CON + c * 12;
            uint2 v0 = *(const uint2*)(row + 0);
            uint2 v1 = *(const uint2*)(row + 4);
            uint2 v2 = *(const uint2*)(row + 8);
            acc2(v0.x, a0, a1);  acc2(v0.y, a2, a3);
            acc2(v1.x, a4, a5);  acc2(v1.y, a6, a7);
            acc2(v2.x, a8, a9);  acc2(v2.y, a10, a11);
        }
    }
    float inv = 1.0f / fmaxf((float)deg, 1.0f);
    ushort* o = agg + (size_t)g * D_CON + c * 12;
    uint2 w0, w1, w2;
    w0.x = packbf(a0 * inv, a1 * inv);   w0.y = packbf(a2 * inv, a3 * inv);
    w1.x = packbf(a4 * inv, a5 * inv);   w1.y = packbf(a6 * inv, a7 * inv);
    w2.x = packbf(a8 * inv, a9 * inv);   w2.y = packbf(a10 * inv, a11 * inv);
    *(uint2*)(o + 0) = w0;
    *(uint2*)(o + 4) = w1;
    *(uint2*)(o + 8) = w2;
}

// -------------------- MFMA bf16 GEMM + bias + relu (double-buffered pipeline) --------------------
__global__ __launch_bounds__(256) void gemm_kernel(
    const ushort* __restrict__ aggp, const ushort* __restrict__ aggq,
    const float* __restrict__ xlic, const ushort* __restrict__ Bpk,
    const float* __restrict__ bias, float* __restrict__ out)
{
    __shared__ __align__(16) ushort As[2][64 * 40];
    __shared__ __align__(16) ushort Bs[2][256 * 40];

    const int t = threadIdx.x;
    const int m0 = blockIdx.x * 64;
    const int lane = t & 63;
    const int wave = t >> 6;
    const int arow = t >> 2;
    const int achk = t & 3;
    const int l15 = lane & 15;
    const int lh  = lane >> 4;

    f32x4 acc[4][4];
    #pragma unroll
    for (int i = 0; i < 4; i++)
        #pragma unroll
        for (int j = 0; j < 4; j++)
            acc[i][j] = (f32x4){0.f, 0.f, 0.f, 0.f};

    uint4 pb0, pb1, pb2, pb3, pa0, pa1;

    #define REG_LOAD(k0)                                                                     \
    {                                                                                        \
        pb0 = *(const uint4*)(Bpk + (size_t)(arow +   0) * 576 + (k0) + achk * 8);           \
        pb1 = *(const uint4*)(Bpk + (size_t)(arow +  64) * 576 + (k0) + achk * 8);           \
        pb2 = *(const uint4*)(Bpk + (size_t)(arow + 128) * 576 + (k0) + achk * 8);           \
        pb3 = *(const uint4*)(Bpk + (size_t)(arow + 192) * 576 + (k0) + achk * 8);           \
        if ((k0) < 128) {                                                                    \
            pa0 = *(const uint4*)(aggp + (size_t)(m0 + arow) * 128 + (k0) + achk * 8);       \
        } else if ((k0) < 320) {                                                             \
            pa0 = *(const uint4*)(aggq + (size_t)(m0 + arow) * 192 + ((k0) - 128) + achk * 8); \
        } else {                                                                             \
            const float* src_ = xlic + (size_t)(m0 + arow) * 256 + ((k0) - 320) + achk * 8;  \
            pa0 = *(const uint4*)(src_ + 0);                                                 \
            pa1 = *(const uint4*)(src_ + 4);                                                 \
        }                                                                                    \
    }

    #define LDS_WRITE(b, k0)                                                                 \
    {                                                                                        \
        uint4 aw;                                                                            \
        if ((k0) < 320) aw = pa0;                                                            \
        else {                                                                               \
            union { uint4 u; float f[4]; } c0, c1;                                           \
            c0.u = pa0; c1.u = pa1;                                                          \
            aw.x = packbf(c0.f[0], c0.f[1]);                                                 \
            aw.y = packbf(c0.f[2], c0.f[3]);                                                 \
            aw.z = packbf(c1.f[0], c1.f[1]);                                                 \
            aw.w = packbf(c1.f[2], c1.f[3]);                                                 \
        }                                                                                    \
        *(uint4*)(&As[b][arow * 40 + achk * 8]) = aw;                                        \
        *(uint4*)(&Bs[b][(arow +   0) * 40 + achk * 8]) = pb0;                               \
        *(uint4*)(&Bs[b][(arow +  64) * 40 + achk * 8]) = pb1;                               \
        *(uint4*)(&Bs[b][(arow + 128) * 40 + achk * 8]) = pb2;                               \
        *(uint4*)(&Bs[b][(arow + 192) * 40 + achk * 8]) = pb3;                               \
    }

    #define COMPUTE(b)                                                                       \
    {                                                                                        \
        bf16x8 af[4], bfr[4];                                                                \
        _Pragma("unroll")                                                                    \
        for (int mt = 0; mt < 4; mt++)                                                       \
            af[mt] = *(const bf16x8*)(&As[b][(mt * 16 + l15) * 40 + lh * 8]);                \
        _Pragma("unroll")                                                                    \
        for (int nt = 0; nt < 4; nt++)                                                       \
            bfr[nt] = *(const bf16x8*)(&Bs[b][(wave * 64 + nt * 16 + l15) * 40 + lh * 8]);   \
        _Pragma("unroll")                                                                    \
        for (int mt = 0; mt < 4; mt++)                                                       \
            _Pragma("unroll")                                                                \
            for (int nt = 0; nt < 4; nt++)                                                   \
                acc[mt][nt] = __builtin_amdgcn_mfma_f32_16x16x32_bf16(af[mt], bfr[nt], acc[mt][nt], 0, 0, 0); \
    }

    REG_LOAD(0);
    LDS_WRITE(0, 0);
    __syncthreads();

    int cur = 0;
    for (int k0 = 32; k0 < 576; k0 += 32) {
        REG_LOAD(k0);
        COMPUTE(cur);
        LDS_WRITE(cur ^ 1, k0);
        __syncthreads();
        cur ^= 1;
    }
    COMPUTE(cur);

    #pragma unroll
    for (int nt = 0; nt < 4; nt++) {
        int n = wave * 64 + nt * 16 + l15;
        float bv = bias[n];
        #pragma unroll
        for (int mt = 0; mt < 4; mt++) {
            #pragma unroll
            for (int r = 0; r < 4; r++) {
                int m = m0 + mt * 16 + lh * 4 + r;
                float v = 0.5f * (acc[mt][nt][r] + bv);
                out[(size_t)m * 256 + n] = fmaxf(v, 0.f);
            }
        }
    }
    #undef REG_LOAD
    #undef LDS_WRITE
    #undef COMPUTE
}

// -------------------- launch --------------------
extern "C" void kernel_launch(void* const* d_in, const int* in_sizes, int n_in,
                              void* d_out, int out_size, void* d_ws, size_t ws_size,
                              hipStream_t stream) {
    const float* x_lic = (const float*)d_in[0];
    const float* x_emp = (const float*)d_in[1];
    const float* x_con = (const float*)d_in[2];
    const float* Wl_p  = (const float*)d_in[3];
    const float* Wr_p  = (const float*)d_in[4];
    const float* b_p   = (const float*)d_in[5];
    const float* Wl_q  = (const float*)d_in[6];
    const float* Wr_q  = (const float*)d_in[7];
    const float* b_q   = (const float*)d_in[8];
    const int* ei_p_src = (const int*)d_in[9];
    const int* ei_p_dst = (const int*)d_in[10];
    const int* ei_q_src = (const int*)d_in[11];
    const int* ei_q_dst = (const int*)d_in[12];

    float* ws = (float*)d_ws;
    ushort* aggp = (ushort*)(ws + OFF_AGGP);
    ushort* aggq = (ushort*)(ws + OFF_AGGQ);   // aliases xe (xe dead after aggP)
    uint*  stg  = (uint*)(ws + OFF_STG);       // aliases aggp
    ushort* xe   = (ushort*)(ws + OFF_XE);
    ushort* xc   = (ushort*)(ws + OFF_XC);
    ushort* Bpk  = (ushort*)(ws + OFF_BPK);
    float* bias  = ws + OFF_BIAS;
    int* cnt  = (int*)(ws + OFF_CNT);
    int* segt = (int*)(ws + OFF_SEGT);
    int* segb = (int*)(ws + OFF_SEGB);
    int* segc = (int*)(ws + OFF_SEGC);
    int* offp = (int*)(ws + OFF_OFFP);
    int* offq = (int*)(ws + OFF_OFFQ);
    int* srtp = (int*)(ws + OFF_SRTP);
    int* srtq = (int*)(ws + OFF_SRTQ);
    float* out = (float*)d_out;

    hipMemsetAsync(segt, 0, SEGW * sizeof(int), stream);

    prep_kernel<<<(256 * 576 + 256 + 255) / 256, 256, 0, stream>>>(Wl_p, Wl_q, Wr_p, Wr_q, b_p, b_q, Bpk, bias);

    // fused convert || precount (independent work, one dispatch)
    conv_pre_kernel<<<NBPRE + (C_XE + C_XC) / 256, 256, 0, stream>>>(
        x_emp, x_con, xe, xc, ei_p_dst, ei_q_dst, segt);

    segbase_kernel<<<1, 64, 0, stream>>>(segt, segb, segc);
    partition_kernel<<<NBPRE, 256, 0, stream>>>(ei_p_src, ei_p_dst, ei_q_src, ei_q_dst, segc, stg);

    sort_kernel<<<SEGW, 1024, 0, stream>>>(segb, segc, stg, srtp, srtq, offp, offq, cnt);

    // aggP first (consumes xe), then aggQ (writes aggq INTO xe's space) — alias-safe order
    aggP_kernel<<<N_LIC / 16, 256, 0, stream>>>(xe, offp, cnt, srtp, aggp);
    aggQ_kernel<<<N_LIC / 16, 256, 0, stream>>>(xc, offq, cnt + N_LIC, srtq, aggq);

    gemm_kernel<<<N_LIC / 64, 256, 0, stream>>>(aggp, aggq, x_lic, Bpk, bias, out);
}